// Round 12
// baseline (62.536 us; speedup 1.0000x reference)
//
#include <hip/hip_runtime.h>

// Holt-Winters round 12: contiguous-burst loads/stores + LDS row<->lane
// transpose, SIMPLE schedule (R11 concept, de-risked).
// 512 blocks x 64 threads (2 blocks/CU); block owns 16 rows.
// Every global access is a ~1KB contiguous burst within ONE row (one instr =
// one row), instead of the 8KB-strided 64-line gathers of R2-R10 that capped
// the memory system at ~1.9 TB/s.
// Per 240-col window k:
//   1. issue 16 asm global_load_dwordx4: tile k+1, row j cols 4*lane (async)
//   2. compute 240 steps; x read per 4-step group straight from LDS tile k
//      (plain C++ ds_reads; buf index = 4G+E only -> chunk loop is runtime,
//       rule #20 safe)
//   3. s_waitcnt vmcnt(0)  (loads from step 1 resident; stores from window
//      k-1 long complete -- a full window of compute sits between)
//   4. stage G -> LDS tile (k+1)&1
//   5. drain window k from ot as 16 asm row-burst stores
// All LDS dep chains are compiler-visible (same-object alias ordering).
// Requires N % 16 == 0 (N=8192 ok); T % 4 == 0.

typedef float f32x4 __attribute__((ext_vector_type(4)));

#define ALOAD(DST, PTR) \
  asm volatile("global_load_dwordx4 %0, %1, off" : "=v"(DST) : "v"(PTR));
#define ASTORE(PTR, VAL) \
  asm volatile("global_store_dwordx4 %0, %1, off" :: "v"(PTR), "v"(VAL));
#define WAITVM0 \
  { asm volatile("s_waitcnt vmcnt(0)" ::: "memory"); \
    __builtin_amdgcn_sched_barrier(0); }

#define ROWD  244                 // LDS row stride (dwords)
#define TILED (16 * ROWD)         // tile size (dwords)

__global__ __launch_bounds__(64, 1) void hw_kernel(
    const float* __restrict__ temp,
    const float* __restrict__ alpha,
    const float* __restrict__ beta,
    const float* __restrict__ gamma,
    const float* __restrict__ L0,
    const float* __restrict__ b0,
    const float* __restrict__ S0,
    float* __restrict__ out,
    int N, int T)
{
    __shared__ __align__(16) float xs[2 * TILED];  // 31.2 KB, two x tiles
    __shared__ __align__(16) float ot[TILED];      // 15.6 KB, out tile

    const int lane = threadIdx.x;
    const int row0 = blockIdx.x * 16;
    const int r    = lane & 15;
    const int row  = row0 + r;

    const float* gld = temp + (size_t)row0 * T + 4 * lane;  // lane = col slot
    float*       gst = out  + (size_t)row0 * T + 4 * lane;

    f32x4 G0,G1,G2,G3,G4,G5,G6,G7,G8,G9,G10,G11,G12,G13,G14,G15;

#define ISSUE(CB, WDT) { if (4*lane < (WDT)) { \
    const float* q_ = gld + (CB); \
    ALOAD(G0 ,q_) q_ += T; ALOAD(G1 ,q_) q_ += T; ALOAD(G2 ,q_) q_ += T; \
    ALOAD(G3 ,q_) q_ += T; ALOAD(G4 ,q_) q_ += T; ALOAD(G5 ,q_) q_ += T; \
    ALOAD(G6 ,q_) q_ += T; ALOAD(G7 ,q_) q_ += T; ALOAD(G8 ,q_) q_ += T; \
    ALOAD(G9 ,q_) q_ += T; ALOAD(G10,q_) q_ += T; ALOAD(G11,q_) q_ += T; \
    ALOAD(G12,q_) q_ += T; ALOAD(G13,q_) q_ += T; ALOAD(G14,q_) q_ += T; \
    ALOAD(G15,q_) } }

#define STAGE(SEL, WDT) { if (4*lane < (WDT)) { \
    float* w_ = xs + (SEL)*TILED + 4*lane; \
    *(f32x4*)(w_+ 0*ROWD)=G0;  *(f32x4*)(w_+ 1*ROWD)=G1;  \
    *(f32x4*)(w_+ 2*ROWD)=G2;  *(f32x4*)(w_+ 3*ROWD)=G3;  \
    *(f32x4*)(w_+ 4*ROWD)=G4;  *(f32x4*)(w_+ 5*ROWD)=G5;  \
    *(f32x4*)(w_+ 6*ROWD)=G6;  *(f32x4*)(w_+ 7*ROWD)=G7;  \
    *(f32x4*)(w_+ 8*ROWD)=G8;  *(f32x4*)(w_+ 9*ROWD)=G9;  \
    *(f32x4*)(w_+10*ROWD)=G10; *(f32x4*)(w_+11*ROWD)=G11; \
    *(f32x4*)(w_+12*ROWD)=G12; *(f32x4*)(w_+13*ROWD)=G13; \
    *(f32x4*)(w_+14*ROWD)=G14; *(f32x4*)(w_+15*ROWD)=G15; } }

    // ---- prologue: stage tile 0; load state ----
    const int wdt0 = (T < 240) ? T : 240;
    ISSUE(0, wdt0)

    const float a_ = alpha[0], bt = beta[0], g_ = gamma[0];
    const float oma = 1.0f - a_, omb = 1.0f - bt, opb = 1.0f + bt;

    float buf[24];
    {
        const float* s0r = S0 + (size_t)row * 24;
        #pragma unroll
        for (int p = 0; p < 6; ++p) {
            const f32x4 v = *reinterpret_cast<const f32x4*>(s0r + 4*p);
            buf[4*p]=v.x; buf[4*p+1]=v.y; buf[4*p+2]=v.z; buf[4*p+3]=v.w;
        }
    }
    float L = L0[row];
    float c = L + b0[row];
    float og0, og1, og2, og3;

    WAITVM0
    STAGE(0, wdt0)

    // step at t = (240-window base) + 24*cc + 4*G + E; phase = 4G+E (static).
#define GSTEPE(G_, E_, XE) { \
    const float x_ = (XE); \
    const float s_ = buf[4*(G_)+(E_)]; \
    const float d_ = x_ - s_; \
    const float Ln = fmaf(oma, c, a_ * d_); \
    const float t1 = fmaf(omb, c, -L); \
    const float cn = fmaf(opb, Ln, t1); \
    const float sn = fmaf(g_, d_ - Ln, s_); \
    buf[4*(G_)+(E_)] = sn; \
    og##E_ = cn * sn; \
    L = Ln; c = cn; }

#define GROUP(G_, XV, OFFD) { \
    GSTEPE(G_,0,(XV).x) GSTEPE(G_,1,(XV).y) GSTEPE(G_,2,(XV).z) GSTEPE(G_,3,(XV).w) \
    if (lane < 16) *reinterpret_cast<f32x4*>(otr + (OFFD) + 4*(G_)) = \
        (f32x4){og0,og1,og2,og3}; }

    const int NW = T / 240;              // 8 full windows for T=2048

    for (int k = 0; k < NW; ++k) {
        const int cb = 240 * (k + 1);
        int wdt = T - cb; if (wdt > 240) wdt = 240;
        ISSUE(cb, wdt)                               // async tile k+1

        const float* xb  = xs + (k & 1) * TILED + r * ROWD;
        float*       otr = ot + r * ROWD;

        for (int cc = 0; cc < 10; ++cc) {
            const int od = 24 * cc;
            const f32x4 v0 = *reinterpret_cast<const f32x4*>(xb + od);
            const f32x4 v1 = *reinterpret_cast<const f32x4*>(xb + od + 4);
            const f32x4 v2 = *reinterpret_cast<const f32x4*>(xb + od + 8);
            const f32x4 v3 = *reinterpret_cast<const f32x4*>(xb + od + 12);
            const f32x4 v4 = *reinterpret_cast<const f32x4*>(xb + od + 16);
            const f32x4 v5 = *reinterpret_cast<const f32x4*>(xb + od + 20);
            if (k == 0 && cc == 0) {
                // t=0 special: out[:,0] = (L0+b0)*S0[:,0]; then t=1..3
                og0 = c * buf[0];
                GSTEPE(0,1,v0.y) GSTEPE(0,2,v0.z) GSTEPE(0,3,v0.w)
                if (lane < 16) *reinterpret_cast<f32x4*>(otr) =
                    (f32x4){og0,og1,og2,og3};
            } else {
                GROUP(0, v0, od)
            }
            GROUP(1, v1, od) GROUP(2, v2, od) GROUP(3, v3, od)
            GROUP(4, v4, od) GROUP(5, v5, od)
        }

        WAITVM0                                      // tile k+1 loads resident
        STAGE((k & 1) ^ 1, wdt)

        // drain window k: 16 contiguous 960B row stores (lanes 0..59)
        if (lane < 60) {
            const float* o2 = ot + 4 * lane;
            float* q_ = gst + 240 * k;
            f32x4 d_;
            d_=*(const f32x4*)(o2+ 0*ROWD); ASTORE(q_,d_) q_+=T;
            d_=*(const f32x4*)(o2+ 1*ROWD); ASTORE(q_,d_) q_+=T;
            d_=*(const f32x4*)(o2+ 2*ROWD); ASTORE(q_,d_) q_+=T;
            d_=*(const f32x4*)(o2+ 3*ROWD); ASTORE(q_,d_) q_+=T;
            d_=*(const f32x4*)(o2+ 4*ROWD); ASTORE(q_,d_) q_+=T;
            d_=*(const f32x4*)(o2+ 5*ROWD); ASTORE(q_,d_) q_+=T;
            d_=*(const f32x4*)(o2+ 6*ROWD); ASTORE(q_,d_) q_+=T;
            d_=*(const f32x4*)(o2+ 7*ROWD); ASTORE(q_,d_) q_+=T;
            d_=*(const f32x4*)(o2+ 8*ROWD); ASTORE(q_,d_) q_+=T;
            d_=*(const f32x4*)(o2+ 9*ROWD); ASTORE(q_,d_) q_+=T;
            d_=*(const f32x4*)(o2+10*ROWD); ASTORE(q_,d_) q_+=T;
            d_=*(const f32x4*)(o2+11*ROWD); ASTORE(q_,d_) q_+=T;
            d_=*(const f32x4*)(o2+12*ROWD); ASTORE(q_,d_) q_+=T;
            d_=*(const f32x4*)(o2+13*ROWD); ASTORE(q_,d_) q_+=T;
            d_=*(const f32x4*)(o2+14*ROWD); ASTORE(q_,d_) q_+=T;
            d_=*(const f32x4*)(o2+15*ROWD); ASTORE(q_,d_)
        }
    }

    // ---- tail: t = 240*NW .. T-1 (128 steps for T=2048) ----
    const int TB  = 240 * NW;
    const int rem = T - TB;
    if (rem > 0) {
        const float* xb  = xs + (NW & 1) * TILED + r * ROWD;
        float*       otr = ot + r * ROWD;
        for (int cc = 0; 24 * cc < rem; ++cc) {
            const int od = 24 * cc;
            const int tb2 = TB + od;
            const f32x4 v0 = *reinterpret_cast<const f32x4*>(xb + od);
            const f32x4 v1 = *reinterpret_cast<const f32x4*>(xb + od + 4);
            const f32x4 v2 = *reinterpret_cast<const f32x4*>(xb + od + 8);
            const f32x4 v3 = *reinterpret_cast<const f32x4*>(xb + od + 12);
            const f32x4 v4 = *reinterpret_cast<const f32x4*>(xb + od + 16);
            const f32x4 v5 = *reinterpret_cast<const f32x4*>(xb + od + 20);
            if (tb2 +  0 < T) { GROUP(0, v0, od) }
            if (tb2 +  4 < T) { GROUP(1, v1, od) }
            if (tb2 +  8 < T) { GROUP(2, v2, od) }
            if (tb2 + 12 < T) { GROUP(3, v3, od) }
            if (tb2 + 16 < T) { GROUP(4, v4, od) }
            if (tb2 + 20 < T) { GROUP(5, v5, od) }
        }
        if (4 * lane < rem) {
            const float* o2 = ot + 4 * lane;
            float* q_ = gst + TB;
            f32x4 d_;
            d_=*(const f32x4*)(o2+ 0*ROWD); ASTORE(q_,d_) q_+=T;
            d_=*(const f32x4*)(o2+ 1*ROWD); ASTORE(q_,d_) q_+=T;
            d_=*(const f32x4*)(o2+ 2*ROWD); ASTORE(q_,d_) q_+=T;
            d_=*(const f32x4*)(o2+ 3*ROWD); ASTORE(q_,d_) q_+=T;
            d_=*(const f32x4*)(o2+ 4*ROWD); ASTORE(q_,d_) q_+=T;
            d_=*(const f32x4*)(o2+ 5*ROWD); ASTORE(q_,d_) q_+=T;
            d_=*(const f32x4*)(o2+ 6*ROWD); ASTORE(q_,d_) q_+=T;
            d_=*(const f32x4*)(o2+ 7*ROWD); ASTORE(q_,d_) q_+=T;
            d_=*(const f32x4*)(o2+ 8*ROWD); ASTORE(q_,d_) q_+=T;
            d_=*(const f32x4*)(o2+ 9*ROWD); ASTORE(q_,d_) q_+=T;
            d_=*(const f32x4*)(o2+10*ROWD); ASTORE(q_,d_) q_+=T;
            d_=*(const f32x4*)(o2+11*ROWD); ASTORE(q_,d_) q_+=T;
            d_=*(const f32x4*)(o2+12*ROWD); ASTORE(q_,d_) q_+=T;
            d_=*(const f32x4*)(o2+13*ROWD); ASTORE(q_,d_) q_+=T;
            d_=*(const f32x4*)(o2+14*ROWD); ASTORE(q_,d_) q_+=T;
            d_=*(const f32x4*)(o2+15*ROWD); ASTORE(q_,d_)
        }
    }

#undef GSTEPE
#undef GROUP
#undef ISSUE
#undef STAGE
}

extern "C" void kernel_launch(void* const* d_in, const int* in_sizes, int n_in,
                              void* d_out, int out_size, void* d_ws, size_t ws_size,
                              hipStream_t stream) {
    const float* temp  = (const float*)d_in[0];
    const float* alpha = (const float*)d_in[1];
    const float* beta  = (const float*)d_in[2];
    const float* gamma = (const float*)d_in[3];
    const float* L0    = (const float*)d_in[4];
    const float* b0    = (const float*)d_in[5];
    const float* S0    = (const float*)d_in[6];
    float* out = (float*)d_out;

    const int N = in_sizes[4];          // 8192
    const int T = in_sizes[0] / N;      // 2048

    const int grid = (N + 15) / 16;     // 512 blocks -> 2 per CU
    hw_kernel<<<grid, 64, 0, stream>>>(
        temp, alpha, beta, gamma, L0, b0, S0, out, N, T);
}